// Round 1
// baseline (533.180 us; speedup 1.0000x reference)
//
#include <hip/hip_runtime.h>

#define FEAT 128
#define NDATA 100000
#define KP1 16385            // NCE_K + 1
#define BSZ 64
#define PTOT (BSZ * KP1)     // 1,048,640

__global__ __launch_bounds__(256) void embed_kernel(
    const float* __restrict__ fs, const float* __restrict__ ft,
    const float* __restrict__ Ws, const float* __restrict__ bs,
    const float* __restrict__ Wt, const float* __restrict__ bt,
    float* __restrict__ vs, float* __restrict__ vt)
{
    __shared__ __align__(16) float sf[1024];
    __shared__ __align__(16) float tf[2048];
    __shared__ float sq[256];
    const int b = blockIdx.x;
    const int t = threadIdx.x;
    for (int i = t; i < 1024; i += 256) sf[i] = fs[b * 1024 + i];
    for (int i = t; i < 2048; i += 256) tf[i] = ft[b * 2048 + i];
    __syncthreads();

    const int d = t & 127;
    float acc;
    if (t < 128) {
        acc = bs[d];
        const float4* w = (const float4*)(Ws + (size_t)d * 1024);
        const float4* x = (const float4*)sf;
        #pragma unroll 4
        for (int i = 0; i < 256; ++i) {
            float4 wv = w[i], xv = x[i];
            acc = fmaf(wv.x, xv.x, acc);
            acc = fmaf(wv.y, xv.y, acc);
            acc = fmaf(wv.z, xv.z, acc);
            acc = fmaf(wv.w, xv.w, acc);
        }
    } else {
        acc = bt[d];
        const float4* w = (const float4*)(Wt + (size_t)d * 2048);
        const float4* x = (const float4*)tf;
        #pragma unroll 4
        for (int i = 0; i < 512; ++i) {
            float4 wv = w[i], xv = x[i];
            acc = fmaf(wv.x, xv.x, acc);
            acc = fmaf(wv.y, xv.y, acc);
            acc = fmaf(wv.z, xv.z, acc);
            acc = fmaf(wv.w, xv.w, acc);
        }
    }

    sq[t] = acc * acc;
    __syncthreads();
    for (int s2 = 64; s2 >= 1; s2 >>= 1) {
        if ((t & 127) < s2) sq[t] += sq[t + s2];
        __syncthreads();
    }
    const float nrm = sqrtf(sq[t < 128 ? 0 : 128]);
    const float v = acc / nrm;
    if (t < 128) vs[b * 128 + d] = v;
    else         vt[b * 128 + d] = v;
}

// One half-wave (32 lanes x float4 = 512B) per (b,k) row per bank.
__global__ __launch_bounds__(256) void gather_kernel(
    const int* __restrict__ idx, const int* __restrict__ cidx,
    const float* __restrict__ mem1, const float* __restrict__ mem2,
    const float* __restrict__ vs, const float* __restrict__ vt,
    float* __restrict__ es, float* __restrict__ et,
    float* __restrict__ sums)
{
    const int lane = threadIdx.x & 63;
    const int wid  = threadIdx.x >> 6;
    const int half = lane >> 5;
    const int l32  = lane & 31;
    const int b    = blockIdx.y;

    const float4 vtv = ((const float4*)(vt + b * 128))[l32];
    const float4 vsv = ((const float4*)(vs + b * 128))[l32];

    const int waveIdx = blockIdx.x * 4 + wid;
    const int nWaves  = gridDim.x * 4;
    const int pos     = idx[b];
    const int* crow   = cidx + (size_t)b * KP1;

    const float invT = 1.0f / 0.07f;
    float acc_t = 0.0f, acc_s = 0.0f;

    for (int k0 = waveIdx * 2; k0 < KP1; k0 += nWaves * 2) {
        const int kk = k0 + half;
        const bool active = (kk < KP1);
        int row = 0;
        if (active) row = (kk == 0) ? pos : crow[kk];

        const float4 a1 = ((const float4*)(mem1 + (size_t)row * 128))[l32];
        const float4 a2 = ((const float4*)(mem2 + (size_t)row * 128))[l32];

        float dt = a1.x * vtv.x;
        dt = fmaf(a1.y, vtv.y, dt);
        dt = fmaf(a1.z, vtv.z, dt);
        dt = fmaf(a1.w, vtv.w, dt);
        float ds = a2.x * vsv.x;
        ds = fmaf(a2.y, vsv.y, ds);
        ds = fmaf(a2.z, vsv.z, ds);
        ds = fmaf(a2.w, vsv.w, ds);

        #pragma unroll
        for (int off = 1; off < 32; off <<= 1) {
            dt += __shfl_xor(dt, off);
            ds += __shfl_xor(ds, off);
        }

        if (l32 == 0 && active) {
            const float e_t = __expf(dt * invT);
            const float e_s = __expf(ds * invT);
            et[(size_t)b * KP1 + kk] = e_t;
            es[(size_t)b * KP1 + kk] = e_s;
            acc_t += e_t;
            acc_s += e_s;
        }
    }

    acc_t += __shfl_xor(acc_t, 32);
    acc_s += __shfl_xor(acc_s, 32);
    if (lane == 0) {
        atomicAdd(&sums[0], acc_s);
        atomicAdd(&sums[1], acc_t);
    }
}

__global__ __launch_bounds__(256) void loss_kernel(
    const float* __restrict__ es, const float* __restrict__ et,
    const float* __restrict__ sums, float* __restrict__ out)
{
    const float c   = 16384.0f / 100000.0f + 1e-7f;
    const float mPn = 16384.0f / 100000.0f;
    const float zscale = 100000.0f / (float)PTOT;  // Z = sum * N / P
    const float invZs = 1.0f / (sums[0] * zscale);
    const float invZt = 1.0f / (sums[1] * zscale);

    float local = 0.0f;
    for (int p = blockIdx.x * blockDim.x + threadIdx.x; p < PTOT;
         p += gridDim.x * blockDim.x) {
        const int k = p - (p / KP1) * KP1;
        const float xs = es[p] * invZs;
        const float xt = et[p] * invZt;
        if (k == 0) {
            local += logf(xs / (xs + c)) + logf(xt / (xt + c));
        } else {
            local += logf(mPn / (xs + c)) + logf(mPn / (xt + c));
        }
    }

    #pragma unroll
    for (int off = 1; off < 64; off <<= 1) local += __shfl_xor(local, off);
    __shared__ float ls[4];
    if ((threadIdx.x & 63) == 0) ls[threadIdx.x >> 6] = local;
    __syncthreads();
    if (threadIdx.x == 0) {
        const float tot = ls[0] + ls[1] + ls[2] + ls[3];
        atomicAdd(out, -tot * (1.0f / 64.0f));
    }
}

extern "C" void kernel_launch(void* const* d_in, const int* in_sizes, int n_in,
                              void* d_out, int out_size, void* d_ws, size_t ws_size,
                              hipStream_t stream) {
    const float* fs   = (const float*)d_in[0];
    const float* ft   = (const float*)d_in[1];
    const int*   idx  = (const int*)d_in[2];
    const int*   cidx = (const int*)d_in[3];
    const float* Ws   = (const float*)d_in[4];
    const float* bs   = (const float*)d_in[5];
    const float* Wt   = (const float*)d_in[6];
    const float* bt   = (const float*)d_in[7];
    const float* m1   = (const float*)d_in[8];
    const float* m2   = (const float*)d_in[9];
    float* out = (float*)d_out;

    float* ws   = (float*)d_ws;
    float* vs   = ws;                 // 64*128
    float* vt   = ws + 8192;          // 64*128
    float* es   = ws + 16384;         // PTOT
    float* et   = es + PTOT;          // PTOT
    float* sums = et + PTOT;          // 2

    hipMemsetAsync(sums, 0, 2 * sizeof(float), stream);
    hipMemsetAsync(out, 0, sizeof(float), stream);

    embed_kernel<<<dim3(64), dim3(256), 0, stream>>>(fs, ft, Ws, bs, Wt, bt, vs, vt);
    gather_kernel<<<dim3(32, 64), dim3(256), 0, stream>>>(idx, cidx, m1, m2, vs, vt, es, et, sums);
    loss_kernel<<<dim3(512), dim3(256), 0, stream>>>(es, et, sums, out);
}

// Round 2
// 512.640 us; speedup vs baseline: 1.0401x; 1.0401x over previous
//
#include <hip/hip_runtime.h>

#define FEAT 128
#define NDATA 100000
#define KP1 16385            // NCE_K + 1
#define BSZ 64
#define PTOT (BSZ * KP1)     // 1,048,640
#define NB 391               // ceil(NDATA / 256)

__device__ __forceinline__ float wave_reduce64(float v) {
    #pragma unroll
    for (int off = 32; off >= 1; off >>= 1) v += __shfl_xor(v, off);
    return v;
}

__device__ __forceinline__ int row_of(int p, const int* __restrict__ idx,
                                      const int* __restrict__ cidx) {
    int b = p / KP1;
    int k = p - b * KP1;
    return (k == 0) ? idx[b] : cidx[p];
}

// ---------------- embed: one block per batch row, coalesced W reads ----------
__global__ __launch_bounds__(256) void embed_kernel(
    const float* __restrict__ fs, const float* __restrict__ ft,
    const float* __restrict__ Ws, const float* __restrict__ bs,
    const float* __restrict__ Wt, const float* __restrict__ bt,
    float* __restrict__ vs, float* __restrict__ vt)
{
    __shared__ __align__(16) float4 xs[256];   // 1024 floats
    __shared__ __align__(16) float4 xt[512];   // 2048 floats
    __shared__ float dots[256];                // [0:128)=s, [128:256)=t
    __shared__ float sq[256];

    const int b = blockIdx.x;
    const int t = threadIdx.x;
    const int wave = t >> 6;
    const int lane = t & 63;

    xs[t] = ((const float4*)(fs + b * 1024))[t];
    xt[t] = ((const float4*)(ft + b * 2048))[t];
    xt[t + 256] = ((const float4*)(ft + b * 2048))[t + 256];
    __syncthreads();

    // s-side: wave handles rows [wave*32, wave*32+32)
    for (int r = 0; r < 32; ++r) {
        const int d = wave * 32 + r;
        const float4* wrow = (const float4*)(Ws + (size_t)d * 1024);
        float acc = 0.0f;
        #pragma unroll
        for (int i = 0; i < 4; ++i) {
            float4 wv = wrow[i * 64 + lane];
            float4 xv = xs[i * 64 + lane];
            acc = fmaf(wv.x, xv.x, acc);
            acc = fmaf(wv.y, xv.y, acc);
            acc = fmaf(wv.z, xv.z, acc);
            acc = fmaf(wv.w, xv.w, acc);
        }
        acc = wave_reduce64(acc);
        if (lane == 0) dots[d] = acc + bs[d];
    }
    // t-side
    for (int r = 0; r < 32; ++r) {
        const int d = wave * 32 + r;
        const float4* wrow = (const float4*)(Wt + (size_t)d * 2048);
        float acc = 0.0f;
        #pragma unroll
        for (int i = 0; i < 8; ++i) {
            float4 wv = wrow[i * 64 + lane];
            float4 xv = xt[i * 64 + lane];
            acc = fmaf(wv.x, xv.x, acc);
            acc = fmaf(wv.y, xv.y, acc);
            acc = fmaf(wv.z, xv.z, acc);
            acc = fmaf(wv.w, xv.w, acc);
        }
        acc = wave_reduce64(acc);
        if (lane == 0) dots[128 + d] = acc + bt[d];
    }
    __syncthreads();

    sq[t] = dots[t] * dots[t];
    __syncthreads();
    for (int s2 = 64; s2 >= 1; s2 >>= 1) {
        if ((t & 127) < s2) sq[t] += sq[t + s2];
        __syncthreads();
    }
    const float nrm = sqrtf(sq[t < 128 ? 0 : 128]);
    const float v = dots[t] / nrm;
    if (t < 128) vs[b * 128 + t] = v;
    else         vt[b * 128 + (t - 128)] = v;
}

// ---------------- CSR build: histogram, scan, scatter ------------------------
__global__ __launch_bounds__(256) void hist_kernel(
    const int* __restrict__ idx, const int* __restrict__ cidx,
    int* __restrict__ hist)
{
    for (int p = blockIdx.x * 256 + threadIdx.x; p < PTOT; p += gridDim.x * 256)
        atomicAdd(&hist[row_of(p, idx, cidx)], 1);
}

__global__ __launch_bounds__(256) void scan1_kernel(
    const int* __restrict__ hist, int* __restrict__ bsum)
{
    __shared__ int ws4[4];
    const int g = blockIdx.x * 256 + threadIdx.x;
    float v = (g < NDATA) ? (float)hist[g] : 0.0f;
    v = wave_reduce64(v);
    if ((threadIdx.x & 63) == 0) ws4[threadIdx.x >> 6] = (int)v;
    __syncthreads();
    if (threadIdx.x == 0) bsum[blockIdx.x] = ws4[0] + ws4[1] + ws4[2] + ws4[3];
}

__global__ __launch_bounds__(512) void scan2_kernel(
    int* __restrict__ bsum, int* __restrict__ offsets)
{
    __shared__ int s[512];
    const int t = threadIdx.x;
    s[t] = (t < NB) ? bsum[t] : 0;
    __syncthreads();
    for (int off = 1; off < 512; off <<= 1) {
        int add = (t >= off) ? s[t - off] : 0;
        __syncthreads();
        s[t] += add;
        __syncthreads();
    }
    if (t < NB) bsum[t] = (t == 0) ? 0 : s[t - 1];   // exclusive block offsets
    if (t == NB - 1) offsets[NDATA] = s[t];          // grand total
}

__global__ __launch_bounds__(256) void scan3_kernel(
    int* __restrict__ hist, const int* __restrict__ bsum,
    int* __restrict__ offsets)
{
    __shared__ int s[256];
    const int t = threadIdx.x;
    const int g = blockIdx.x * 256 + t;
    const int h = (g < NDATA) ? hist[g] : 0;
    s[t] = h;
    __syncthreads();
    for (int off = 1; off < 256; off <<= 1) {
        int add = (t >= off) ? s[t - off] : 0;
        __syncthreads();
        s[t] += add;
        __syncthreads();
    }
    const int ex = (t == 0) ? 0 : s[t - 1];
    const int o = bsum[blockIdx.x] + ex;
    if (g < NDATA) {
        offsets[g] = o;
        hist[g] = o;    // becomes the scatter cursor
    }
}

__global__ __launch_bounds__(256) void scatter_kernel(
    const int* __restrict__ idx, const int* __restrict__ cidx,
    int* __restrict__ cursor, unsigned* __restrict__ pairs)
{
    for (int p = blockIdx.x * 256 + threadIdx.x; p < PTOT; p += gridDim.x * 256) {
        const int r = row_of(p, idx, cidx);
        const int pos = atomicAdd(&cursor[r], 1);
        pairs[pos] = (unsigned)p;
    }
}

// ---------------- main: stream banks once, one wave per row ------------------
__global__ __launch_bounds__(1024, 8) void pair_gather_kernel(
    const float* __restrict__ mem1, const float* __restrict__ mem2,
    const float* __restrict__ vs, const float* __restrict__ vt,
    const int* __restrict__ offsets, const unsigned* __restrict__ pairs,
    float* __restrict__ es, float* __restrict__ et,
    float* __restrict__ sums)
{
    __shared__ __align__(16) float4 vT[2048];  // [b][l32], 32 KB
    __shared__ __align__(16) float4 vS[2048];
    __shared__ float waveAcc[32];

    const int t = threadIdx.x;
    vT[t]        = ((const float4*)vt)[t];
    vT[t + 1024] = ((const float4*)vt)[t + 1024];
    vS[t]        = ((const float4*)vs)[t];
    vS[t + 1024] = ((const float4*)vs)[t + 1024];
    __syncthreads();

    const int wave = t >> 6;
    const int lane = t & 63;
    const int half = lane >> 5;   // 0: bank1 x v_t -> et ; 1: bank2 x v_s -> es
    const int l32  = lane & 31;

    const float* bank = half ? mem2 : mem1;
    const float4* vtab = half ? vS : vT;
    float* eout = half ? es : et;
    const float invT = 1.0f / 0.07f;

    float acc = 0.0f;
    const int rowStride = gridDim.x * 16;
    const int nIter = (NDATA + rowStride - 1) / rowStride;

    for (int it = 0; it < nIter; ++it) {
        const int row = blockIdx.x * 16 + wave + it * rowStride;
        if (row < NDATA) {
            const float4 a = ((const float4*)(bank + (size_t)row * 128))[l32];
            const int o0 = offsets[row];
            const int o1 = offsets[row + 1];
            for (int j = o0; j < o1; ++j) {
                const unsigned p = pairs[j];
                const unsigned b = p / (unsigned)KP1;
                const float4 vv = vtab[b * 32 + l32];
                float d = a.x * vv.x;
                d = fmaf(a.y, vv.y, d);
                d = fmaf(a.z, vv.z, d);
                d = fmaf(a.w, vv.w, d);
                #pragma unroll
                for (int off = 16; off >= 1; off >>= 1) d += __shfl_xor(d, off);
                if (l32 == 0) {
                    const float e = __expf(d * invT);
                    eout[p] = e;
                    acc += e;
                }
            }
        }
    }

    if (l32 == 0) waveAcc[wave * 2 + half] = acc;
    __syncthreads();
    if (t < 2) {
        float s = 0.0f;
        #pragma unroll
        for (int i = 0; i < 16; ++i) s += waveAcc[i * 2 + t];
        atomicAdd(&sums[t == 0 ? 1 : 0], s);  // half0 -> et -> sums[1]
    }
}

// ---------------- loss -------------------------------------------------------
__global__ __launch_bounds__(256) void loss_kernel(
    const float* __restrict__ es, const float* __restrict__ et,
    const float* __restrict__ sums, float* __restrict__ out)
{
    const float c      = 16384.0f / 100000.0f + 1e-7f;
    const float logmPn = -1.80886495f;           // ln(16384/100000)
    const float invZs  = ((float)PTOT / (float)NDATA) / sums[0];
    const float invZt  = ((float)PTOT / (float)NDATA) / sums[1];

    const int b = blockIdx.y;
    const int k = blockIdx.x * 256 + threadIdx.x;
    float local = 0.0f;
    if (k < KP1) {
        const int p = b * KP1 + k;
        const float xs = es[p] * invZs;
        const float xt = et[p] * invZt;
        local = -__logf(xs + c) - __logf(xt + c);
        if (k == 0) local += __logf(xs) + __logf(xt);
        else        local += 2.0f * logmPn;
    }
    local = wave_reduce64(local);
    __shared__ float ls[4];
    if ((threadIdx.x & 63) == 0) ls[threadIdx.x >> 6] = local;
    __syncthreads();
    if (threadIdx.x == 0) {
        const float tot = ls[0] + ls[1] + ls[2] + ls[3];
        atomicAdd(out, -tot * (1.0f / 64.0f));
    }
}

extern "C" void kernel_launch(void* const* d_in, const int* in_sizes, int n_in,
                              void* d_out, int out_size, void* d_ws, size_t ws_size,
                              hipStream_t stream) {
    const float* fs   = (const float*)d_in[0];
    const float* ft   = (const float*)d_in[1];
    const int*   idx  = (const int*)d_in[2];
    const int*   cidx = (const int*)d_in[3];
    const float* Ws   = (const float*)d_in[4];
    const float* bs   = (const float*)d_in[5];
    const float* Wt   = (const float*)d_in[6];
    const float* bt   = (const float*)d_in[7];
    const float* m1   = (const float*)d_in[8];
    const float* m2   = (const float*)d_in[9];
    float* out = (float*)d_out;

    float* ws      = (float*)d_ws;
    float* vs      = ws;                        // 8192
    float* vt      = vs + 8192;                 // 8192
    float* es      = vt + 8192;                 // PTOT
    float* et      = es + PTOT;                 // PTOT
    float* sums    = et + PTOT;                 // 2 (+2 pad)
    int*   hist    = (int*)(sums + 4);          // NDATA (cursor after scan3)
    int*   offsets = hist + NDATA;              // NDATA + 1
    int*   bsum    = offsets + NDATA + 1;       // NB (+pad)
    unsigned* pairs = (unsigned*)(bsum + NB + 1); // PTOT

    hipMemsetAsync(hist, 0, NDATA * sizeof(int), stream);
    hipMemsetAsync(sums, 0, 2 * sizeof(float), stream);
    hipMemsetAsync(out, 0, sizeof(float), stream);

    embed_kernel<<<dim3(64), dim3(256), 0, stream>>>(fs, ft, Ws, bs, Wt, bt, vs, vt);
    hist_kernel<<<dim3(2048), dim3(256), 0, stream>>>(idx, cidx, hist);
    scan1_kernel<<<dim3(NB), dim3(256), 0, stream>>>(hist, bsum);
    scan2_kernel<<<dim3(1), dim3(512), 0, stream>>>(bsum, offsets);
    scan3_kernel<<<dim3(NB), dim3(256), 0, stream>>>(hist, bsum, offsets);
    scatter_kernel<<<dim3(2048), dim3(256), 0, stream>>>(idx, cidx, hist, pairs);
    pair_gather_kernel<<<dim3(512), dim3(1024), 0, stream>>>(
        m1, m2, vs, vt, offsets, pairs, es, et, sums);
    loss_kernel<<<dim3(65, 64), dim3(256), 0, stream>>>(es, et, sums, out);
}

// Round 3
// 373.386 us; speedup vs baseline: 1.4280x; 1.3729x over previous
//
#include <hip/hip_runtime.h>

#define FEAT 128
#define NDATA 100000
#define KP1 16385            // NCE_K + 1
#define BSZ 64
#define PTOT (BSZ * KP1)     // 1,048,640
#define NROW_TILES 1563      // ceil(NDATA / 64)

__device__ __forceinline__ float wave_reduce64(float v) {
    #pragma unroll
    for (int off = 32; off >= 1; off >>= 1) v += __shfl_xor(v, off);
    return v;
}

// ---------------- embed: one block per batch row, coalesced W reads ----------
__global__ __launch_bounds__(256) void embed_kernel(
    const float* __restrict__ fs, const float* __restrict__ ft,
    const float* __restrict__ Ws, const float* __restrict__ bs,
    const float* __restrict__ Wt, const float* __restrict__ bt,
    float* __restrict__ vs, float* __restrict__ vt)
{
    __shared__ __align__(16) float4 xs[256];   // 1024 floats
    __shared__ __align__(16) float4 xt[512];   // 2048 floats
    __shared__ float dots[256];                // [0:128)=s, [128:256)=t
    __shared__ float sq[256];

    const int b = blockIdx.x;
    const int t = threadIdx.x;
    const int wave = t >> 6;
    const int lane = t & 63;

    xs[t] = ((const float4*)(fs + b * 1024))[t];
    xt[t] = ((const float4*)(ft + b * 2048))[t];
    xt[t + 256] = ((const float4*)(ft + b * 2048))[t + 256];
    __syncthreads();

    for (int r = 0; r < 32; ++r) {
        const int d = wave * 32 + r;
        const float4* wrow = (const float4*)(Ws + (size_t)d * 1024);
        float acc = 0.0f;
        #pragma unroll
        for (int i = 0; i < 4; ++i) {
            float4 wv = wrow[i * 64 + lane];
            float4 xv = xs[i * 64 + lane];
            acc = fmaf(wv.x, xv.x, acc);
            acc = fmaf(wv.y, xv.y, acc);
            acc = fmaf(wv.z, xv.z, acc);
            acc = fmaf(wv.w, xv.w, acc);
        }
        acc = wave_reduce64(acc);
        if (lane == 0) dots[d] = acc + bs[d];
    }
    for (int r = 0; r < 32; ++r) {
        const int d = wave * 32 + r;
        const float4* wrow = (const float4*)(Wt + (size_t)d * 2048);
        float acc = 0.0f;
        #pragma unroll
        for (int i = 0; i < 8; ++i) {
            float4 wv = wrow[i * 64 + lane];
            float4 xv = xt[i * 64 + lane];
            acc = fmaf(wv.x, xv.x, acc);
            acc = fmaf(wv.y, xv.y, acc);
            acc = fmaf(wv.z, xv.z, acc);
            acc = fmaf(wv.w, xv.w, acc);
        }
        acc = wave_reduce64(acc);
        if (lane == 0) dots[128 + d] = acc + bt[d];
    }
    __syncthreads();

    sq[t] = dots[t] * dots[t];
    __syncthreads();
    for (int s2 = 64; s2 >= 1; s2 >>= 1) {
        if ((t & 127) < s2) sq[t] += sq[t + s2];
        __syncthreads();
    }
    const float nrm = sqrtf(sq[t < 128 ? 0 : 128]);
    const float v = dots[t] / nrm;
    if (t < 128) vs[b * 128 + t] = v;
    else         vt[b * 128 + (t - 128)] = v;
}

// ---------------- dense GEMM: S[b][row] = dot(bank[row], v[b]) --------------
// grid: (NROW_TILES, 2); block 256. Tile 64 rows x 64 b, K=128.
// Micro-tile 4x4 per thread with stride-16 interleave (conflict-free b128).
#define LDA 132   // 128 + 4 float pad, keeps float4 alignment
__global__ __launch_bounds__(256) void sgemm_kernel(
    const float* __restrict__ m1, const float* __restrict__ m2,
    const float* __restrict__ vs, const float* __restrict__ vt,
    float* __restrict__ S1, float* __restrict__ S2)
{
    __shared__ __align__(16) float A[64 * LDA];
    __shared__ __align__(16) float V[64 * LDA];

    const int t = threadIdx.x;
    const int bank = blockIdx.y;
    const float* __restrict__ bankp = bank ? m2 : m1;
    const float* __restrict__ vp    = bank ? vs : vt;
    float* __restrict__ Sp          = bank ? S2 : S1;
    const int row0 = blockIdx.x * 64;

    // stage A tile (64 rows x 128) and V (64 b x 128), coalesced float4
    for (int q = t; q < 2048; q += 256) {
        const int r = q >> 5, c = q & 31;
        int gr = row0 + r; if (gr >= NDATA) gr = NDATA - 1;
        const float4 av = ((const float4*)(bankp + (size_t)gr * 128))[c];
        *(float4*)&A[r * LDA + c * 4] = av;
        const float4 vv = ((const float4*)(vp + r * 128))[c];
        *(float4*)&V[r * LDA + c * 4] = vv;
    }
    __syncthreads();

    const int rb = t & 15;     // rows rb, rb+16, rb+32, rb+48
    const int cb = t >> 4;     // cols cb, cb+16, cb+32, cb+48
    float acc[4][4] = {{0.f}};

    #pragma unroll 2
    for (int kc = 0; kc < 32; ++kc) {
        float4 a[4], v[4];
        #pragma unroll
        for (int i = 0; i < 4; ++i)
            a[i] = *(const float4*)&A[(rb + 16 * i) * LDA + kc * 4];
        #pragma unroll
        for (int j = 0; j < 4; ++j)
            v[j] = *(const float4*)&V[(cb + 16 * j) * LDA + kc * 4];
        #pragma unroll
        for (int i = 0; i < 4; ++i)
            #pragma unroll
            for (int j = 0; j < 4; ++j) {
                acc[i][j] = fmaf(a[i].x, v[j].x, acc[i][j]);
                acc[i][j] = fmaf(a[i].y, v[j].y, acc[i][j]);
                acc[i][j] = fmaf(a[i].z, v[j].z, acc[i][j]);
                acc[i][j] = fmaf(a[i].w, v[j].w, acc[i][j]);
            }
    }

    #pragma unroll
    for (int j = 0; j < 4; ++j) {
        const int bb = cb + 16 * j;
        #pragma unroll
        for (int i = 0; i < 4; ++i) {
            const int row = row0 + rb + 16 * i;
            if (row < NDATA) Sp[(size_t)bb * NDATA + row] = acc[i][j];
        }
    }
}

// ---------------- gather + exp + partial sums --------------------------------
__global__ __launch_bounds__(256) void gather_exp_kernel(
    const int* __restrict__ idx, const int* __restrict__ cidx,
    const float* __restrict__ S1, const float* __restrict__ S2,
    float* __restrict__ es, float* __restrict__ et,
    float* __restrict__ sums)
{
    const int b = blockIdx.y;
    const float* __restrict__ s1b = S1 + (size_t)b * NDATA;
    const float* __restrict__ s2b = S2 + (size_t)b * NDATA;
    const float invT = 1.0f / 0.07f;

    float acc_s = 0.0f, acc_t = 0.0f;
    const int base = blockIdx.x * 1024;
    #pragma unroll
    for (int j = 0; j < 4; ++j) {
        const int k = base + j * 256 + threadIdx.x;
        if (k < KP1) {
            const int row = (k == 0) ? idx[b] : cidx[b * KP1 + k];
            const float e_t = __expf(s1b[row] * invT);
            const float e_s = __expf(s2b[row] * invT);
            et[(size_t)b * KP1 + k] = e_t;
            es[(size_t)b * KP1 + k] = e_s;
            acc_t += e_t;
            acc_s += e_s;
        }
    }

    acc_s = wave_reduce64(acc_s);
    acc_t = wave_reduce64(acc_t);
    __shared__ float ls[8];
    if ((threadIdx.x & 63) == 0) {
        ls[(threadIdx.x >> 6) * 2]     = acc_s;
        ls[(threadIdx.x >> 6) * 2 + 1] = acc_t;
    }
    __syncthreads();
    if (threadIdx.x == 0)
        atomicAdd(&sums[0], ls[0] + ls[2] + ls[4] + ls[6]);
    if (threadIdx.x == 1)
        atomicAdd(&sums[1], ls[1] + ls[3] + ls[5] + ls[7]);
}

// ---------------- loss -------------------------------------------------------
__global__ __launch_bounds__(256) void loss_kernel(
    const float* __restrict__ es, const float* __restrict__ et,
    const float* __restrict__ sums, float* __restrict__ out)
{
    const float c      = 16384.0f / 100000.0f + 1e-7f;
    const float logmPn = -1.80886495f;           // ln(16384/100000)
    const float invZs  = ((float)PTOT / (float)NDATA) / sums[0];
    const float invZt  = ((float)PTOT / (float)NDATA) / sums[1];

    const int b = blockIdx.y;
    const int k = blockIdx.x * 256 + threadIdx.x;
    float local = 0.0f;
    if (k < KP1) {
        const int p = b * KP1 + k;
        const float xs = es[p] * invZs;
        const float xt = et[p] * invZt;
        local = -__logf(xs + c) - __logf(xt + c);
        if (k == 0) local += __logf(xs) + __logf(xt);
        else        local += 2.0f * logmPn;
    }
    local = wave_reduce64(local);
    __shared__ float ls[4];
    if ((threadIdx.x & 63) == 0) ls[threadIdx.x >> 6] = local;
    __syncthreads();
    if (threadIdx.x == 0) {
        const float tot = ls[0] + ls[1] + ls[2] + ls[3];
        atomicAdd(out, -tot * (1.0f / 64.0f));
    }
}

extern "C" void kernel_launch(void* const* d_in, const int* in_sizes, int n_in,
                              void* d_out, int out_size, void* d_ws, size_t ws_size,
                              hipStream_t stream) {
    const float* fs   = (const float*)d_in[0];
    const float* ft   = (const float*)d_in[1];
    const int*   idx  = (const int*)d_in[2];
    const int*   cidx = (const int*)d_in[3];
    const float* Ws   = (const float*)d_in[4];
    const float* bs   = (const float*)d_in[5];
    const float* Wt   = (const float*)d_in[6];
    const float* bt   = (const float*)d_in[7];
    const float* m1   = (const float*)d_in[8];
    const float* m2   = (const float*)d_in[9];
    float* out = (float*)d_out;

    float* ws   = (float*)d_ws;
    float* vs   = ws;                     // 8192
    float* vt   = vs + 8192;              // 8192
    float* es   = vt + 8192;              // PTOT
    float* et   = es + PTOT;              // PTOT
    float* sums = et + PTOT;              // 2 (+2 pad)
    float* S1   = sums + 4;               // 64 * NDATA
    float* S2   = S1 + (size_t)BSZ * NDATA;

    hipMemsetAsync(sums, 0, 2 * sizeof(float), stream);
    hipMemsetAsync(out, 0, sizeof(float), stream);

    embed_kernel<<<dim3(64), dim3(256), 0, stream>>>(fs, ft, Ws, bs, Wt, bt, vs, vt);
    sgemm_kernel<<<dim3(NROW_TILES, 2), dim3(256), 0, stream>>>(m1, m2, vs, vt, S1, S2);
    gather_exp_kernel<<<dim3(17, 64), dim3(256), 0, stream>>>(idx, cidx, S1, S2, es, et, sums);
    loss_kernel<<<dim3(65, 64), dim3(256), 0, stream>>>(es, et, sums, out);
}

// Round 4
// 272.653 us; speedup vs baseline: 1.9555x; 1.3695x over previous
//
#include <hip/hip_runtime.h>

#define FEAT 128
#define NDATA 100000
#define KP1 16385            // NCE_K + 1
#define BSZ 64
#define PTOT (BSZ * KP1)     // 1,048,640
#define NROW_TILES 1563      // ceil(NDATA / 64)
#define LDB 136              // bf16 LDS row stride (elements): 272B, 16B-aligned

typedef short short8 __attribute__((ext_vector_type(8)));
typedef float f32x4 __attribute__((ext_vector_type(4)));

__device__ __forceinline__ float wave_reduce64(float v) {
    #pragma unroll
    for (int off = 32; off >= 1; off >>= 1) v += __shfl_xor(v, off);
    return v;
}

__device__ __forceinline__ unsigned short f2bf(float f) {
    unsigned u = __float_as_uint(f);
    u += 0x7FFFu + ((u >> 16) & 1u);   // round-to-nearest-even
    return (unsigned short)(u >> 16);
}

// ---------------- embed: one block/batch row, 16 waves, coalesced W reads ----
__global__ __launch_bounds__(1024) void embed_kernel(
    const float* __restrict__ fs, const float* __restrict__ ft,
    const float* __restrict__ Ws, const float* __restrict__ bs,
    const float* __restrict__ Wt, const float* __restrict__ bt,
    float* __restrict__ vs, float* __restrict__ vt)
{
    __shared__ __align__(16) float4 xs[256];   // 1024 floats
    __shared__ __align__(16) float4 xt[512];   // 2048 floats
    __shared__ float dots[256];                // [0:128)=s, [128:256)=t
    __shared__ float sq[256];

    const int b = blockIdx.x;
    const int t = threadIdx.x;
    const int wave = t >> 6;
    const int lane = t & 63;

    if (t < 256)              xs[t]       = ((const float4*)(fs + b * 1024))[t];
    else if (t < 768)         xt[t - 256] = ((const float4*)(ft + b * 2048))[t - 256];
    __syncthreads();

    // s-side: wave handles 8 rows
    #pragma unroll
    for (int r = 0; r < 8; ++r) {
        const int d = wave * 8 + r;
        const float4* wrow = (const float4*)(Ws + (size_t)d * 1024);
        float acc = 0.0f;
        #pragma unroll
        for (int i = 0; i < 4; ++i) {
            float4 wv = wrow[i * 64 + lane];
            float4 xv = xs[i * 64 + lane];
            acc = fmaf(wv.x, xv.x, acc);
            acc = fmaf(wv.y, xv.y, acc);
            acc = fmaf(wv.z, xv.z, acc);
            acc = fmaf(wv.w, xv.w, acc);
        }
        acc = wave_reduce64(acc);
        if (lane == 0) dots[d] = acc + bs[d];
    }
    // t-side
    #pragma unroll
    for (int r = 0; r < 8; ++r) {
        const int d = wave * 8 + r;
        const float4* wrow = (const float4*)(Wt + (size_t)d * 2048);
        float acc = 0.0f;
        #pragma unroll
        for (int i = 0; i < 8; ++i) {
            float4 wv = wrow[i * 64 + lane];
            float4 xv = xt[i * 64 + lane];
            acc = fmaf(wv.x, xv.x, acc);
            acc = fmaf(wv.y, xv.y, acc);
            acc = fmaf(wv.z, xv.z, acc);
            acc = fmaf(wv.w, xv.w, acc);
        }
        acc = wave_reduce64(acc);
        if (lane == 0) dots[128 + d] = acc + bt[d];
    }
    __syncthreads();

    if (t < 256) sq[t] = dots[t] * dots[t];
    __syncthreads();
    for (int s2 = 64; s2 >= 1; s2 >>= 1) {
        if (t < 256 && (t & 127) < s2) sq[t] += sq[t + s2];
        __syncthreads();
    }
    if (t < 256) {
        const float nrm = sqrtf(sq[t < 128 ? 0 : 128]);
        const float v = dots[t] / nrm;
        if (t < 128) vs[b * 128 + t] = v;
        else         vt[b * 128 + (t - 128)] = v;
    }
}

// ---------------- bf16 MFMA GEMM: S[row][b] = dot(bank[row], v[b]) ----------
// grid (NROW_TILES, 2); block 256 (4 waves). Tile 64 rows x 64 b, K=128.
__global__ __launch_bounds__(256, 4) void sgemm_kernel(
    const float* __restrict__ m1, const float* __restrict__ m2,
    const float* __restrict__ vs, const float* __restrict__ vt,
    float* __restrict__ S1, float* __restrict__ S2)
{
    __shared__ __align__(16) unsigned short As[64 * LDB];
    __shared__ __align__(16) unsigned short Vs[64 * LDB];

    const int t = threadIdx.x;
    const int bank = blockIdx.y;
    const float* __restrict__ bankp = bank ? m2 : m1;
    const float* __restrict__ vp    = bank ? vs : vt;
    float* __restrict__ Sp          = bank ? S2 : S1;
    const int row0 = blockIdx.x * 64;

    // stage tiles, fp32 -> bf16
    #pragma unroll
    for (int q = t; q < 2048; q += 256) {
        const int r = q >> 5, c = q & 31;
        int gr = row0 + r; if (gr >= NDATA) gr = NDATA - 1;
        const float4 av = ((const float4*)(bankp + (size_t)gr * 128))[c];
        ushort4 a4; a4.x = f2bf(av.x); a4.y = f2bf(av.y); a4.z = f2bf(av.z); a4.w = f2bf(av.w);
        *(ushort4*)&As[r * LDB + c * 4] = a4;
        const float4 vv = ((const float4*)(vp + r * 128))[c];
        ushort4 v4; v4.x = f2bf(vv.x); v4.y = f2bf(vv.y); v4.z = f2bf(vv.z); v4.w = f2bf(vv.w);
        *(ushort4*)&Vs[r * LDB + c * 4] = v4;
    }
    __syncthreads();

    const int m0 = (t >> 6) * 16;      // wave row-tile
    const int lane = t & 63;
    const int m = lane & 15;           // A row / B col / D col index
    const int q4 = lane >> 4;          // quad: A/B k-offset q4*8; D rows q4*4+r

    short8 a[4];
    #pragma unroll
    for (int kk = 0; kk < 4; ++kk)
        a[kk] = *(const short8*)&As[(m0 + m) * LDB + kk * 32 + q4 * 8];

    #pragma unroll
    for (int n0 = 0; n0 < 64; n0 += 16) {
        f32x4 acc = {0.f, 0.f, 0.f, 0.f};
        #pragma unroll
        for (int kk = 0; kk < 4; ++kk) {
            short8 bv = *(const short8*)&Vs[(n0 + m) * LDB + kk * 32 + q4 * 8];
            acc = __builtin_amdgcn_mfma_f32_16x16x32_bf16(a[kk], bv, acc, 0, 0, 0);
        }
        #pragma unroll
        for (int r = 0; r < 4; ++r) {
            const int row = row0 + m0 + q4 * 4 + r;
            if (row < NDATA) Sp[(size_t)row * 64 + n0 + m] = acc[r];
        }
    }
}

// ---------------- gather + exp + partial sums (ILP 8) ------------------------
__global__ __launch_bounds__(256) void gather_exp_kernel(
    const int* __restrict__ idx, const int* __restrict__ cidx,
    const float* __restrict__ S1, const float* __restrict__ S2,
    float* __restrict__ es, float* __restrict__ et,
    float* __restrict__ sums)
{
    const int b = blockIdx.y;
    const int base = blockIdx.x * 2048;
    const float invT = 1.0f / 0.07f;

    int rows[8];
    #pragma unroll
    for (int j = 0; j < 8; ++j) {
        const int k = base + j * 256 + threadIdx.x;
        rows[j] = (k < KP1) ? ((k == 0) ? idx[b] : cidx[b * KP1 + k]) : -1;
    }
    float d1[8], d2[8];
    #pragma unroll
    for (int j = 0; j < 8; ++j) {
        if (rows[j] >= 0) {
            d1[j] = S1[(size_t)rows[j] * 64 + b];
            d2[j] = S2[(size_t)rows[j] * 64 + b];
        }
    }
    float acc_s = 0.0f, acc_t = 0.0f;
    #pragma unroll
    for (int j = 0; j < 8; ++j) {
        if (rows[j] >= 0) {
            const int k = base + j * 256 + threadIdx.x;
            const float e_t = __expf(d1[j] * invT);
            const float e_s = __expf(d2[j] * invT);
            et[(size_t)b * KP1 + k] = e_t;
            es[(size_t)b * KP1 + k] = e_s;
            acc_t += e_t;
            acc_s += e_s;
        }
    }

    acc_s = wave_reduce64(acc_s);
    acc_t = wave_reduce64(acc_t);
    __shared__ float ls[8];
    if ((threadIdx.x & 63) == 0) {
        ls[(threadIdx.x >> 6) * 2]     = acc_s;
        ls[(threadIdx.x >> 6) * 2 + 1] = acc_t;
    }
    __syncthreads();
    if (threadIdx.x == 0) atomicAdd(&sums[0], ls[0] + ls[2] + ls[4] + ls[6]);
    if (threadIdx.x == 1) atomicAdd(&sums[1], ls[1] + ls[3] + ls[5] + ls[7]);
}

// ---------------- loss -------------------------------------------------------
__global__ __launch_bounds__(256) void loss_kernel(
    const float* __restrict__ es, const float* __restrict__ et,
    const float* __restrict__ sums, float* __restrict__ out)
{
    const float c      = 16384.0f / 100000.0f + 1e-7f;
    const float logmPn = -1.80886495f;           // ln(16384/100000)
    const float invZs  = ((float)PTOT / (float)NDATA) / sums[0];
    const float invZt  = ((float)PTOT / (float)NDATA) / sums[1];

    const int b = blockIdx.y;
    const int k = blockIdx.x * 256 + threadIdx.x;
    float local = 0.0f;
    if (k < KP1) {
        const int p = b * KP1 + k;
        const float xs = es[p] * invZs;
        const float xt = et[p] * invZt;
        local = -__logf(xs + c) - __logf(xt + c);
        if (k == 0) local += __logf(xs) + __logf(xt);
        else        local += 2.0f * logmPn;
    }
    local = wave_reduce64(local);
    __shared__ float ls[4];
    if ((threadIdx.x & 63) == 0) ls[threadIdx.x >> 6] = local;
    __syncthreads();
    if (threadIdx.x == 0) {
        const float tot = ls[0] + ls[1] + ls[2] + ls[3];
        atomicAdd(out, -tot * (1.0f / 64.0f));
    }
}

extern "C" void kernel_launch(void* const* d_in, const int* in_sizes, int n_in,
                              void* d_out, int out_size, void* d_ws, size_t ws_size,
                              hipStream_t stream) {
    const float* fs   = (const float*)d_in[0];
    const float* ft   = (const float*)d_in[1];
    const int*   idx  = (const int*)d_in[2];
    const int*   cidx = (const int*)d_in[3];
    const float* Ws   = (const float*)d_in[4];
    const float* bs   = (const float*)d_in[5];
    const float* Wt   = (const float*)d_in[6];
    const float* bt   = (const float*)d_in[7];
    const float* m1   = (const float*)d_in[8];
    const float* m2   = (const float*)d_in[9];
    float* out = (float*)d_out;

    float* ws   = (float*)d_ws;
    float* vs   = ws;                     // 8192
    float* vt   = vs + 8192;              // 8192
    float* es   = vt + 8192;              // PTOT
    float* et   = es + PTOT;              // PTOT
    float* sums = et + PTOT;              // 2 (+2 pad)
    float* S1   = sums + 4;               // NDATA x 64  (row-major by row!)
    float* S2   = S1 + (size_t)NDATA * BSZ;

    hipMemsetAsync(sums, 0, 2 * sizeof(float), stream);
    hipMemsetAsync(out, 0, sizeof(float), stream);

    embed_kernel<<<dim3(64), dim3(1024), 0, stream>>>(fs, ft, Ws, bs, Wt, bt, vs, vt);
    sgemm_kernel<<<dim3(NROW_TILES, 2), dim3(256), 0, stream>>>(m1, m2, vs, vt, S1, S2);
    gather_exp_kernel<<<dim3(9, 64), dim3(256), 0, stream>>>(idx, cidx, S1, S2, es, et, sums);
    loss_kernel<<<dim3(65, 64), dim3(256), 0, stream>>>(es, et, sums, out);
}

// Round 5
// 227.258 us; speedup vs baseline: 2.3461x; 1.1998x over previous
//
#include <hip/hip_runtime.h>

#define FEAT 128
#define NDATA 100000
#define KP1 16385            // NCE_K + 1
#define BSZ 64
#define PTOT (BSZ * KP1)     // 1,048,640
#define NF4 (PTOT / 4)       // 262,160 (exact)
#define NTILES 1563          // ceil(NDATA / 64)
#define LDB 136              // bf16 LDS row stride (elements): 272B, 16B-aligned

typedef short short8 __attribute__((ext_vector_type(8)));
typedef float f32x4 __attribute__((ext_vector_type(4)));

__device__ __forceinline__ float wave_reduce64(float v) {
    #pragma unroll
    for (int off = 32; off >= 1; off >>= 1) v += __shfl_xor(v, off);
    return v;
}

__device__ __forceinline__ unsigned short f2bf(float f) {
    unsigned u = __float_as_uint(f);
    u += 0x7FFFu + ((u >> 16) & 1u);   // round-to-nearest-even
    return (unsigned short)(u >> 16);
}

// ---------------- embed: one block/batch row, 16 waves; also zero-inits ------
__global__ __launch_bounds__(1024) void embed_kernel(
    const float* __restrict__ fs, const float* __restrict__ ft,
    const float* __restrict__ Ws, const float* __restrict__ bs,
    const float* __restrict__ Wt, const float* __restrict__ bt,
    float* __restrict__ vs, float* __restrict__ vt,
    float* __restrict__ sums, float* __restrict__ out)
{
    __shared__ __align__(16) float4 xs[256];   // 1024 floats
    __shared__ __align__(16) float4 xt[512];   // 2048 floats
    __shared__ float dots[256];
    __shared__ float sq[256];

    const int b = blockIdx.x;
    const int t = threadIdx.x;
    const int wave = t >> 6;
    const int lane = t & 63;

    if (b == 0 && t < 2) sums[t] = 0.0f;       // zero accumulators (replaces memsets)
    if (b == 0 && t == 2) out[0] = 0.0f;

    if (t < 256)              xs[t]       = ((const float4*)(fs + b * 1024))[t];
    else if (t < 768)         xt[t - 256] = ((const float4*)(ft + b * 2048))[t - 256];
    __syncthreads();

    #pragma unroll
    for (int r = 0; r < 8; ++r) {
        const int d = wave * 8 + r;
        const float4* wrow = (const float4*)(Ws + (size_t)d * 1024);
        float acc = 0.0f;
        #pragma unroll
        for (int i = 0; i < 4; ++i) {
            float4 wv = wrow[i * 64 + lane];
            float4 xv = xs[i * 64 + lane];
            acc = fmaf(wv.x, xv.x, acc);
            acc = fmaf(wv.y, xv.y, acc);
            acc = fmaf(wv.z, xv.z, acc);
            acc = fmaf(wv.w, xv.w, acc);
        }
        acc = wave_reduce64(acc);
        if (lane == 0) dots[d] = acc + bs[d];
    }
    #pragma unroll
    for (int r = 0; r < 8; ++r) {
        const int d = wave * 8 + r;
        const float4* wrow = (const float4*)(Wt + (size_t)d * 2048);
        float acc = 0.0f;
        #pragma unroll
        for (int i = 0; i < 8; ++i) {
            float4 wv = wrow[i * 64 + lane];
            float4 xv = xt[i * 64 + lane];
            acc = fmaf(wv.x, xv.x, acc);
            acc = fmaf(wv.y, xv.y, acc);
            acc = fmaf(wv.z, xv.z, acc);
            acc = fmaf(wv.w, xv.w, acc);
        }
        acc = wave_reduce64(acc);
        if (lane == 0) dots[128 + d] = acc + bt[d];
    }
    __syncthreads();

    if (t < 256) sq[t] = dots[t] * dots[t];
    __syncthreads();
    for (int s2 = 64; s2 >= 1; s2 >>= 1) {
        if (t < 256 && (t & 127) < s2) sq[t] += sq[t + s2];
        __syncthreads();
    }
    if (t < 256) {
        const float nrm = sqrtf(sq[t < 128 ? 0 : 128]);
        const float v = dots[t] / nrm;
        if (t < 128) vs[b * 128 + t] = v;
        else         vt[b * 128 + (t - 128)] = v;
    }
}

// ---------------- bf16 MFMA GEMM: S[row][b] = dot(bank[row], v[b]) ----------
// grid (391, 2); block 256 (4 waves). Each block: stage V once, loop 4 tiles.
__global__ __launch_bounds__(256, 4) void sgemm_kernel(
    const float* __restrict__ m1, const float* __restrict__ m2,
    const float* __restrict__ vs, const float* __restrict__ vt,
    float* __restrict__ S1, float* __restrict__ S2)
{
    __shared__ __align__(16) unsigned short As[64 * LDB];
    __shared__ __align__(16) unsigned short Vs[64 * LDB];

    const int t = threadIdx.x;
    const int bank = blockIdx.y;
    const float* __restrict__ bankp = bank ? m2 : m1;
    const float* __restrict__ vp    = bank ? vs : vt;
    float* __restrict__ Sp          = bank ? S2 : S1;

    // stage V tile once (64 b x 128), fp32 -> bf16
    #pragma unroll
    for (int q = t; q < 2048; q += 256) {
        const int r = q >> 5, c = q & 31;
        const float4 vv = ((const float4*)(vp + r * 128))[c];
        ushort4 v4; v4.x = f2bf(vv.x); v4.y = f2bf(vv.y); v4.z = f2bf(vv.z); v4.w = f2bf(vv.w);
        *(ushort4*)&Vs[r * LDB + c * 4] = v4;
    }

    const int lane = t & 63;
    const int m0 = (t >> 6) * 16;      // wave row-tile
    const int m  = lane & 15;          // A row / B col / D col
    const int q4 = lane >> 4;          // A/B k-offset q4*8; D rows q4*4+r

    #pragma unroll
    for (int it = 0; it < 4; ++it) {
        const int tile = blockIdx.x * 4 + it;
        if (tile >= NTILES) break;
        const int row0 = tile * 64;

        __syncthreads();   // previous-iter readers done (covers Vs on iter 0)
        #pragma unroll
        for (int q = t; q < 2048; q += 256) {
            const int r = q >> 5, c = q & 31;
            int gr = row0 + r; if (gr >= NDATA) gr = NDATA - 1;
            const float4 av = ((const float4*)(bankp + (size_t)gr * 128))[c];
            ushort4 a4; a4.x = f2bf(av.x); a4.y = f2bf(av.y); a4.z = f2bf(av.z); a4.w = f2bf(av.w);
            *(ushort4*)&As[r * LDB + c * 4] = a4;
        }
        __syncthreads();

        short8 a[4];
        #pragma unroll
        for (int kk = 0; kk < 4; ++kk)
            a[kk] = *(const short8*)&As[(m0 + m) * LDB + kk * 32 + q4 * 8];

        #pragma unroll
        for (int n0 = 0; n0 < 64; n0 += 16) {
            f32x4 acc = {0.f, 0.f, 0.f, 0.f};
            #pragma unroll
            for (int kk = 0; kk < 4; ++kk) {
                short8 bv = *(const short8*)&Vs[(n0 + m) * LDB + kk * 32 + q4 * 8];
                acc = __builtin_amdgcn_mfma_f32_16x16x32_bf16(a[kk], bv, acc, 0, 0, 0);
            }
            #pragma unroll
            for (int r = 0; r < 4; ++r) {
                const int row = row0 + m0 + q4 * 4 + r;
                if (row < NDATA) Sp[(size_t)row * 64 + n0 + m] = acc[r];
            }
        }
    }
}

// ---------------- gather + exp + partial sums (ILP 8) ------------------------
__global__ __launch_bounds__(256) void gather_exp_kernel(
    const int* __restrict__ idx, const int* __restrict__ cidx,
    const float* __restrict__ S1, const float* __restrict__ S2,
    float* __restrict__ es, float* __restrict__ et,
    float* __restrict__ sums)
{
    const int b = blockIdx.y;
    const int base = blockIdx.x * 2048;
    const float invT = 1.0f / 0.07f;

    int rows[8];
    #pragma unroll
    for (int j = 0; j < 8; ++j) {
        const int k = base + j * 256 + threadIdx.x;
        rows[j] = (k < KP1) ? ((k == 0) ? idx[b] : cidx[b * KP1 + k]) : -1;
    }
    float d1[8], d2[8];
    #pragma unroll
    for (int j = 0; j < 8; ++j) {
        if (rows[j] >= 0) {
            d1[j] = S1[(size_t)rows[j] * 64 + b];
            d2[j] = S2[(size_t)rows[j] * 64 + b];
        }
    }
    float acc_s = 0.0f, acc_t = 0.0f;
    #pragma unroll
    for (int j = 0; j < 8; ++j) {
        if (rows[j] >= 0) {
            const int k = base + j * 256 + threadIdx.x;
            const float e_t = __expf(d1[j] * invT);
            const float e_s = __expf(d2[j] * invT);
            et[(size_t)b * KP1 + k] = e_t;
            es[(size_t)b * KP1 + k] = e_s;
            acc_t += e_t;
            acc_s += e_s;
        }
    }

    acc_s = wave_reduce64(acc_s);
    acc_t = wave_reduce64(acc_t);
    __shared__ float ls[8];
    if ((threadIdx.x & 63) == 0) {
        ls[(threadIdx.x >> 6) * 2]     = acc_s;
        ls[(threadIdx.x >> 6) * 2 + 1] = acc_t;
    }
    __syncthreads();
    if (threadIdx.x == 0) atomicAdd(&sums[0], ls[0] + ls[2] + ls[4] + ls[6]);
    if (threadIdx.x == 1) atomicAdd(&sums[1], ls[1] + ls[3] + ls[5] + ls[7]);
}

// ---------------- loss: grid-stride, float4, 1 log per element-pair ----------
// Every element treated as negative: term = 2*ln(mPn) - ln((xs+c)(xt+c)).
// Positive (k==0) correction per b: + ln(xs0*xt0) - 2*ln(mPn).
__global__ __launch_bounds__(256) void loss_kernel(
    const float* __restrict__ es, const float* __restrict__ et,
    const float* __restrict__ sums, float* __restrict__ out)
{
    const float c  = 16384.0f / 100000.0f + 1e-7f;
    const float c2 = 2.0f * -1.80886495f;        // 2*ln(16384/100000)
    const float invZs = ((float)PTOT / (float)NDATA) / sums[0];
    const float invZt = ((float)PTOT / (float)NDATA) / sums[1];

    float local = 0.0f;
    const int stride = gridDim.x * 256;
    for (int i = blockIdx.x * 256 + threadIdx.x; i < NF4; i += stride) {
        const float4 e_s = ((const float4*)es)[i];
        const float4 e_t = ((const float4*)et)[i];
        const float p0 = (e_s.x * invZs + c) * (e_t.x * invZt + c);
        const float p1 = (e_s.y * invZs + c) * (e_t.y * invZt + c);
        const float p2 = (e_s.z * invZs + c) * (e_t.z * invZt + c);
        const float p3 = (e_s.w * invZs + c) * (e_t.w * invZt + c);
        local += (c2 - __logf(p0)) + (c2 - __logf(p1))
               + (c2 - __logf(p2)) + (c2 - __logf(p3));
    }
    if (blockIdx.x == 0 && threadIdx.x < BSZ) {
        const int b = threadIdx.x;
        const float xs0 = es[(size_t)b * KP1] * invZs;
        const float xt0 = et[(size_t)b * KP1] * invZt;
        local += __logf(xs0 * xt0) - c2;
    }

    local = wave_reduce64(local);
    __shared__ float ls[4];
    if ((threadIdx.x & 63) == 0) ls[threadIdx.x >> 6] = local;
    __syncthreads();
    if (threadIdx.x == 0) {
        const float tot = ls[0] + ls[1] + ls[2] + ls[3];
        atomicAdd(out, -tot * (1.0f / 64.0f));
    }
}

extern "C" void kernel_launch(void* const* d_in, const int* in_sizes, int n_in,
                              void* d_out, int out_size, void* d_ws, size_t ws_size,
                              hipStream_t stream) {
    const float* fs   = (const float*)d_in[0];
    const float* ft   = (const float*)d_in[1];
    const int*   idx  = (const int*)d_in[2];
    const int*   cidx = (const int*)d_in[3];
    const float* Ws   = (const float*)d_in[4];
    const float* bs   = (const float*)d_in[5];
    const float* Wt   = (const float*)d_in[6];
    const float* bt   = (const float*)d_in[7];
    const float* m1   = (const float*)d_in[8];
    const float* m2   = (const float*)d_in[9];
    float* out = (float*)d_out;

    float* ws   = (float*)d_ws;
    float* vs   = ws;                     // 8192
    float* vt   = vs + 8192;              // 8192
    float* es   = vt + 8192;              // PTOT (16B-aligned: 16384 floats before)
    float* et   = es + PTOT;              // PTOT (PTOT%4==0 -> aligned)
    float* sums = et + PTOT;              // 2 (+2 pad)
    float* S1   = sums + 4;               // NDATA x 64 (row-major)
    float* S2   = S1 + (size_t)NDATA * BSZ;

    embed_kernel<<<dim3(64), dim3(1024), 0, stream>>>(
        fs, ft, Ws, bs, Wt, bt, vs, vt, sums, out);
    sgemm_kernel<<<dim3(391, 2), dim3(256), 0, stream>>>(m1, m2, vs, vt, S1, S2);
    gather_exp_kernel<<<dim3(9, 64), dim3(256), 0, stream>>>(idx, cidx, S1, S2, es, et, sums);
    loss_kernel<<<dim3(256), dim3(256), 0, stream>>>(es, et, sums, out);
}